// Round 4
// baseline (11704.316 us; speedup 1.0000x reference)
//
#include <hip/hip_runtime.h>
#include <math.h>
#include <stdint.h>

typedef unsigned long long u64;

#define NANCH 36864
#define PRE_NMS 6000
#define POST_NMS 300

// ---- ws layout (BYTE offsets), total ~42.5 MB ----
// rpn holds HALF the batch (4 images) at a time.
#define OFF_RPN   0ull            // f32 [4*512*4096] = 33554432 B
#define OFF_KEYS  33554432ull     // u64 [8*65536]    =  4194304 B
#define OFF_BOX   37748736ull     // f32 [8*36864*4]  =  4718592 B
// end 42467328

#define SCORE_OFF 9600u
#define TGT_OFF   599424u

// ---------------- K1: naive direct conv3x3 + bias + relu ----------------
// grid (16 y-quads, 128 co-quads, 4 b), block 256 = 64x * 4y. 4 co per block.
__global__ __launch_bounds__(256) void conv_naive(const float* __restrict__ F,
                                                  const float* __restrict__ W,
                                                  const float* __restrict__ bias,
                                                  float* __restrict__ rpn,
                                                  int b_base) {
    int t = threadIdx.x;
    int x = t & 63;
    int y = blockIdx.x * 4 + (t >> 6);
    int co0 = blockIdx.y * 4;
    int bl = blockIdx.z;            // local batch 0..3
    int b = b_base + bl;            // global batch

    const float* Fb = F + (size_t)b * 512 * 4096;
    float acc[4] = {0.f, 0.f, 0.f, 0.f};

    for (int ci = 0; ci < 512; ++ci) {
        const float* xp = Fb + (size_t)ci * 4096;
        const float* wp = W + ((size_t)co0 * 512 + ci) * 9;
#pragma unroll
        for (int tap = 0; tap < 9; ++tap) {
            int dy = tap / 3 - 1, dx = tap % 3 - 1;
            int yy = y + dy, xx = x + dx;
            float v = ((unsigned)yy < 64u && (unsigned)xx < 64u) ? xp[yy * 64 + xx] : 0.f;
#pragma unroll
            for (int c = 0; c < 4; ++c)
                acc[c] += wp[(size_t)c * 512 * 9 + tap] * v;
        }
    }
#pragma unroll
    for (int c = 0; c < 4; ++c) {
        int co = co0 + c;
        rpn[((size_t)(bl * 512 + co)) * 4096 + y * 64 + x] = fmaxf(acc[c] + bias[co], 0.f);
    }
}

// ---------------- K2: naive per-pixel 1x1 heads + score/tgt out + keys ----------------
// grid (16 y-quads, 4 b), block 256 = 64x * 4y.
__global__ __launch_bounds__(256) void heads_naive(const float* __restrict__ rpn,
                                                   const float* __restrict__ cls_w,
                                                   const float* __restrict__ cls_b,
                                                   const float* __restrict__ bbox_w,
                                                   const float* __restrict__ bbox_b,
                                                   float* __restrict__ out,
                                                   u64* __restrict__ keys,
                                                   int b_base) {
    int t = threadIdx.x;
    int x = t & 63;
    int y = blockIdx.x * 4 + (t >> 6);
    int bl = blockIdx.y;
    int b = b_base + bl;
    int p = y * 64 + x;

    const float* rb = rpn + (size_t)bl * 512 * 4096 + p;

    float acc[54];
#pragma unroll
    for (int ch = 0; ch < 54; ++ch) acc[ch] = 0.f;

    for (int ci = 0; ci < 512; ++ci) {
        float rv = rb[(size_t)ci * 4096];
#pragma unroll
        for (int ch = 0; ch < 18; ++ch) acc[ch] += cls_w[(size_t)ch * 512 + ci] * rv;
#pragma unroll
        for (int ch = 0; ch < 36; ++ch) acc[18 + ch] += bbox_w[(size_t)ch * 512 + ci] * rv;
    }
#pragma unroll
    for (int ch = 0; ch < 18; ++ch) acc[ch] += cls_b[ch];
#pragma unroll
    for (int ch = 0; ch < 36; ++ch) acc[18 + ch] += bbox_b[ch];

    // raw score / tgt outputs
#pragma unroll
    for (int ch = 0; ch < 18; ++ch)
        out[SCORE_OFF + ((size_t)b * NANCH + (size_t)p * 9 + (ch >> 1)) * 2 + (ch & 1)] = acc[ch];
#pragma unroll
    for (int ch = 0; ch < 36; ++ch)
        out[TGT_OFF + ((size_t)b * NANCH + (size_t)p * 9 + (ch >> 2)) * 4 + (ch & 3)] = acc[18 + ch];

    // f32 softmax -> key = (prob bits << 32) | ~idx   (= lax.top_k order, stable ties)
#pragma unroll
    for (int a = 0; a < 9; ++a) {
        float s0 = acc[2 * a], s1 = acc[2 * a + 1];
        float mm = fmaxf(s0, s1);
        float e0 = expf(s0 - mm);
        float e1 = expf(s1 - mm);
        float pr = e1 / (e0 + e1);
        int idx = p * 9 + a;
        keys[(size_t)b * 65536 + idx] =
            ((u64)__float_as_uint(pr) << 32) | (u64)(0xFFFFFFFFu - (unsigned)idx);
    }
}

// ---------------- K3: pad keys [36864, 65536) with 0 ----------------
__global__ void pad_kernel(u64* __restrict__ keys) {
    int b = blockIdx.y;
    int i = 36864 + blockIdx.x * 256 + threadIdx.x;   // 112*256 = 28672
    keys[(size_t)b * 65536 + i] = 0ull;
}

// ---------------- K4: decode all anchor boxes (np-f32 mirror) ----------------
__global__ void box_kernel(const float* __restrict__ out, float* __restrict__ box) {
    int b = blockIdx.y;
    int i = blockIdx.x * 256 + threadIdx.x;    // 144*256 = 36864
    const float* tg = &out[TGT_OFF + ((size_t)b * NANCH + i) * 4];
    float dyv = tg[0], dxv = tg[1], dhv = tg[2], dwv = tg[3];
    int dim = i >> 12, rem = i & 4095;
    double cxd = (double)(8 + 16 * (rem >> 6));
    double cyd = (double)(8 + 16 * (rem & 63));
    const double sca[3] = {8.0, 16.0, 32.0};
    const double rat[3] = {0.5, 1.0, 2.0};
    double sc = sca[dim / 3], ra = rat[dim % 3];
    double d0 = 16.0 * sc * sqrt(ra);
    double d1 = 16.0 * sc * sqrt(1.0 / ra);
    // ANCHORS: f64 corners rounded once to f32, then pure-f32 decode (np mirror, no FMA)
    float a0 = (float)(cxd - 0.5 * d0);
    float a1 = (float)(cyd - 0.5 * d1);
    float a2 = (float)(cxd + 0.5 * d0);
    float a3 = (float)(cyd + 0.5 * d1);
    float ah = __fsub_rn(a2, a0), aw = __fsub_rn(a3, a1);
    float acy = __fadd_rn(a0, __fmul_rn(0.5f, ah));
    float acx = __fadd_rn(a1, __fmul_rn(0.5f, aw));
    float pcy = __fadd_rn(acy, __fmul_rn(dyv, ah));
    float pcx = __fadd_rn(acx, __fmul_rn(dxv, aw));
    float ph = __fmul_rn(ah, expf(dhv));
    float pw = __fmul_rn(aw, expf(dwv));
    float q0 = fminf(fmaxf(__fsub_rn(pcy, __fmul_rn(0.5f, ph)), 0.f), 1023.f);
    float q1 = fminf(fmaxf(__fsub_rn(pcx, __fmul_rn(0.5f, pw)), 0.f), 1023.f);
    float q2 = fminf(fmaxf(__fadd_rn(pcy, __fmul_rn(0.5f, ph)), 0.f), 1023.f);
    float q3 = fminf(fmaxf(__fadd_rn(pcx, __fmul_rn(0.5f, pw)), 0.f), 1023.f);
    *(float4*)&box[((size_t)b * NANCH + i) * 4] = make_float4(q0, q1, q2, q3);
}

// ---------------- K5: full bitonic sort of 65536 u64 keys per batch (global, 1 WG) ----
__global__ __launch_bounds__(1024) void sort_kernel(u64* __restrict__ keys) {
    u64* K = keys + (size_t)blockIdx.x * 65536;
    int t = threadIdx.x;
    for (int k = 2; k <= 65536; k <<= 1) {
        for (int j = k >> 1; j > 0; j >>= 1) {
            for (int ii = 0; ii < 64; ++ii) {
                int i = t + (ii << 10);
                int l = i ^ j;
                if (l > i) {
                    u64 a = K[i], c = K[l];
                    bool up = ((i & k) == 0);
                    bool sw = up ? (a < c) : (a > c);   // descending overall
                    if (sw) { K[i] = c; K[l] = a; }
                }
            }
            __syncthreads();
        }
    }
}

// ---------------- K6: sequential NMS (np-f32 mirror), one block per batch ----------------
__global__ __launch_bounds__(256) void nms_kernel(const u64* __restrict__ keys,
                                                  const float* __restrict__ box,
                                                  float* __restrict__ out_top) {
    __shared__ u64 rk[4];
    __shared__ int rq[4];
    int b = blockIdx.x, t = threadIdx.x;

    u64 key[24];
    float c0[24], c1[24], c2[24], c3[24], ar[24];
#pragma unroll
    for (int m = 0; m < 24; ++m) {
        int q = t + (m << 8);
        u64 kk = (q < PRE_NMS) ? keys[(size_t)b * 65536 + q] : 0ull;
        key[m] = kk;
        if (kk != 0ull) {
            unsigned idx = 0xFFFFFFFFu - (unsigned)(kk & 0xFFFFFFFFull);
            const float* bp = &box[((size_t)b * NANCH + idx) * 4];
            c0[m] = bp[0]; c1[m] = bp[1]; c2[m] = bp[2]; c3[m] = bp[3];
        } else {
            c0[m] = c1[m] = c2[m] = c3[m] = 0.f;
        }
        ar[m] = __fmul_rn(__fsub_rn(c2[m], c0[m]), __fsub_rn(c3[m], c1[m]));
    }
    __syncthreads();

    for (int it = 0; it < POST_NMS; ++it) {
        u64 bk = 0ull;
        int bq = 0x7fffffff;
#pragma unroll
        for (int m = 0; m < 24; ++m) {
            int q = t + (m << 8);
            if (key[m] > bk) { bk = key[m]; bq = q; }
        }
#pragma unroll
        for (int off = 32; off > 0; off >>= 1) {
            u64 k2 = __shfl_xor(bk, off);
            int q2 = __shfl_xor(bq, off);
            if (k2 > bk || (k2 == bk && q2 < bq)) { bk = k2; bq = q2; }
        }
        if ((t & 63) == 0) { rk[t >> 6] = bk; rq[t >> 6] = bq; }
        __syncthreads();
        u64 fk = rk[0];
        int fq = rq[0];
#pragma unroll
        for (int ww = 1; ww < 4; ++ww)
            if (rk[ww] > fk || (rk[ww] == fk && rq[ww] < fq)) { fk = rk[ww]; fq = rq[ww]; }
        if (fk == 0ull) { fk = keys[(size_t)b * 65536]; }   // all suppressed: ref picks argmax(-inf)=0
        unsigned idxj = 0xFFFFFFFFu - (unsigned)(fk & 0xFFFFFFFFull);
        const float* bjp = &box[((size_t)b * NANCH + idxj) * 4];
        float j0 = bjp[0], j1 = bjp[1], j2 = bjp[2], j3 = bjp[3];
        if (t == 0) {
            float* o = out_top + ((size_t)b * POST_NMS + it) * 4;
            o[0] = floorf(j0); o[1] = floorf(j1); o[2] = floorf(j2); o[3] = floorf(j3);
        }
        float areaj = __fmul_rn(__fsub_rn(j2, j0), __fsub_rn(j3, j1));
#pragma unroll
        for (int m = 0; m < 24; ++m) {
            float yy1 = fmaxf(j0, c0[m]);
            float xx1 = fmaxf(j1, c1[m]);
            float yy2 = fminf(j2, c2[m]);
            float xx2 = fminf(j3, c3[m]);
            float inter = __fmul_rn(fmaxf(__fsub_rn(yy2, yy1), 0.f),
                                    fmaxf(__fsub_rn(xx2, xx1), 0.f));
            float denom = __fadd_rn(__fsub_rn(__fadd_rn(areaj, ar[m]), inter), 1e-9f);
            float iou = __fdiv_rn(inter, denom);
            if (iou >= 0.7f) key[m] = 0ull;
        }
        __syncthreads();
    }
}

extern "C" void kernel_launch(void* const* d_in, const int* in_sizes, int n_in,
                              void* d_out, int out_size, void* d_ws, size_t ws_size,
                              hipStream_t stream) {
    (void)in_sizes; (void)n_in; (void)out_size; (void)ws_size;
    const float* features = (const float*)d_in[0];
    const float* conv_w = (const float*)d_in[1];
    const float* conv_b = (const float*)d_in[2];
    const float* cls_w = (const float*)d_in[3];
    const float* cls_b = (const float*)d_in[4];
    const float* bbox_w = (const float*)d_in[5];
    const float* bbox_b = (const float*)d_in[6];
    float* out = (float*)d_out;
    char* ws = (char*)d_ws;

    float* rpn = (float*)(ws + OFF_RPN);
    u64* keys = (u64*)(ws + OFF_KEYS);
    float* box = (float*)(ws + OFF_BOX);

    // two half-batches through the 33.5MB rpn buffer
    for (int h = 0; h < 2; ++h) {
        int b_base = h * 4;
        conv_naive<<<dim3(16, 128, 4), 256, 0, stream>>>(features, conv_w, conv_b, rpn, b_base);
        heads_naive<<<dim3(16, 4), 256, 0, stream>>>(rpn, cls_w, cls_b, bbox_w, bbox_b,
                                                     out, keys, b_base);
    }
    pad_kernel<<<dim3(112, 8), 256, 0, stream>>>(keys);
    box_kernel<<<dim3(144, 8), 256, 0, stream>>>(out, box);
    sort_kernel<<<8, 1024, 0, stream>>>(keys);
    nms_kernel<<<8, 256, 0, stream>>>(keys, box, out);
}